// Round 3
// baseline (265.042 us; speedup 1.0000x reference)
//
#include <hip/hip_runtime.h>

// GraphAttentionLayer: x(8192,512) f32, support(8192,8192) i32{0,1},
// W(512,256) f32, a(512,1) f32  ->  out(8192,256) f32
//
// Decomposition (softmax shift cancels in numerator/denominator):
//   h = x@W (bf16 MFMA)
//   s = h@a1, t = h@a2, u = s+t
//   top rows i<4096 : out = elu((eL*TL + eR*TR)/(eL*TL[256] + eR*TR[256]))
//   bot rows i>=4096: out = elu(TB/TB[256]),  TB = sup[4096:, :] @ (wb .* [h|1])

typedef short bf16x8 __attribute__((ext_vector_type(8)));
typedef float f32x4 __attribute__((ext_vector_type(4)));

static __device__ __forceinline__ unsigned short f2bf(float f) {
    unsigned int u = __builtin_bit_cast(unsigned int, f);
    unsigned int r = (u + 0x7FFFu + ((u >> 16) & 1u)) >> 16;
    return (unsigned short)r;
}
static __device__ __forceinline__ float bf2f(unsigned short s) {
    unsigned int u = ((unsigned int)s) << 16;
    return __builtin_bit_cast(float, u);
}

// ---- k1a: x f32 -> bf16 row-major [8192][512]
__global__ __launch_bounds__(256) void k_cvt_x(const float* __restrict__ x,
                                               unsigned short* __restrict__ xb) {
    int i = (blockIdx.x * 256 + threadIdx.x) * 4;
    float4 v = *(const float4*)(x + i);
    ushort4 o = make_ushort4(f2bf(v.x), f2bf(v.y), f2bf(v.z), f2bf(v.w));
    *(ushort4*)(xb + i) = o;
}

// ---- k1b: W [512][256] f32 -> Wbt [256][512] bf16 (n-major, k-contiguous)
__global__ __launch_bounds__(256) void k_cvt_w(const float* __restrict__ W,
                                               unsigned short* __restrict__ Wbt) {
    int idx = blockIdx.x * 256 + threadIdx.x;
    int n = idx >> 9, k = idx & 511;
    Wbt[idx] = f2bf(W[k * 256 + n]);
}

// ---- k2: h = xb @ Wbt^T. Writes h row-major bf16 AND B1t [272][8192] rows 0..255.
__global__ __launch_bounds__(256) void k_gemm_h(const unsigned short* __restrict__ xb,
                                                const unsigned short* __restrict__ Wbt,
                                                unsigned short* __restrict__ h,
                                                unsigned short* __restrict__ B1t) {
    __shared__ unsigned short Asm[128][72];
    __shared__ unsigned short Bsm[64][72];
    int tid = threadIdx.x;
    int wv = tid >> 6, ln = tid & 63;
    int m0 = blockIdx.x * 128, n0 = blockIdx.y * 64;

    f32x4 acc[2][4];
#pragma unroll
    for (int i = 0; i < 2; i++)
#pragma unroll
        for (int j = 0; j < 4; j++) acc[i][j] = (f32x4)0.0f;

    for (int k0 = 0; k0 < 512; k0 += 64) {
        {
            int r = tid >> 1, c = (tid & 1) * 32;
            const unsigned short* src = xb + (m0 + r) * 512 + k0 + c;
            *(bf16x8*)&Asm[r][c]      = *(const bf16x8*)(src);
            *(bf16x8*)&Asm[r][c + 8]  = *(const bf16x8*)(src + 8);
            *(bf16x8*)&Asm[r][c + 16] = *(const bf16x8*)(src + 16);
            *(bf16x8*)&Asm[r][c + 24] = *(const bf16x8*)(src + 24);
        }
        {
            int r = tid >> 2, c = (tid & 3) * 16;
            const unsigned short* src = Wbt + (n0 + r) * 512 + k0 + c;
            *(bf16x8*)&Bsm[r][c]     = *(const bf16x8*)(src);
            *(bf16x8*)&Bsm[r][c + 8] = *(const bf16x8*)(src + 8);
        }
        __syncthreads();
        int lr = ln & 15, lk = (ln >> 4) * 8;
#pragma unroll
        for (int ks = 0; ks < 2; ks++) {
            int kk = ks * 32 + lk;
            bf16x8 a0 = *(const bf16x8*)&Asm[wv * 32 + lr][kk];
            bf16x8 a1 = *(const bf16x8*)&Asm[wv * 32 + 16 + lr][kk];
#pragma unroll
            for (int nt = 0; nt < 4; nt++) {
                bf16x8 b = *(const bf16x8*)&Bsm[nt * 16 + lr][kk];
                acc[0][nt] = __builtin_amdgcn_mfma_f32_16x16x32_bf16(a0, b, acc[0][nt], 0, 0, 0);
                acc[1][nt] = __builtin_amdgcn_mfma_f32_16x16x32_bf16(a1, b, acc[1][nt], 0, 0, 0);
            }
        }
        __syncthreads();
    }
    int lr = ln & 15, lrow = (ln >> 4) * 4;
#pragma unroll
    for (int mt = 0; mt < 2; mt++) {
#pragma unroll
        for (int nt = 0; nt < 4; nt++) {
            int mg = m0 + wv * 32 + mt * 16 + lrow;
            int ng = n0 + nt * 16 + lr;
            ushort4 tb = make_ushort4(f2bf(acc[mt][nt][0]), f2bf(acc[mt][nt][1]),
                                      f2bf(acc[mt][nt][2]), f2bf(acc[mt][nt][3]));
            h[(mg + 0) * 256 + ng] = tb.x;
            h[(mg + 1) * 256 + ng] = tb.y;
            h[(mg + 2) * 256 + ng] = tb.z;
            h[(mg + 3) * 256 + ng] = tb.w;
            *(ushort4*)&B1t[ng * 8192 + mg] = tb;
        }
    }
}

// ---- k3: s[j], t[j]
__global__ __launch_bounds__(256) void k_st(const unsigned short* __restrict__ h,
                                            const float* __restrict__ a,
                                            float* __restrict__ s, float* __restrict__ t) {
    int wv = threadIdx.x >> 6, ln = threadIdx.x & 63;
    int j = blockIdx.x * 4 + wv;
    ushort4 hv = *(const ushort4*)(h + j * 256 + ln * 4);
    float4 a1 = *(const float4*)(a + ln * 4);
    float4 a2 = *(const float4*)(a + 256 + ln * 4);
    float s_ = bf2f(hv.x) * a1.x + bf2f(hv.y) * a1.y + bf2f(hv.z) * a1.z + bf2f(hv.w) * a1.w;
    float t_ = bf2f(hv.x) * a2.x + bf2f(hv.y) * a2.y + bf2f(hv.z) * a2.z + bf2f(hv.w) * a2.w;
#pragma unroll
    for (int off = 32; off; off >>= 1) {
        s_ += __shfl_down(s_, off);
        t_ += __shfl_down(t_, off);
    }
    if (ln == 0) { s[j] = s_; t[j] = t_; }
}

// ---- k3b: wb / eL / eR; fill B1t aux rows (256 = ones, 257..271 = 0)
__global__ __launch_bounds__(256) void k_weights(const float* __restrict__ s,
                                                 const float* __restrict__ t,
                                                 float* __restrict__ wb,
                                                 float* __restrict__ eL,
                                                 float* __restrict__ eR,
                                                 unsigned short* __restrict__ B1t) {
    int j = blockIdx.x * 256 + threadIdx.x;
    float eb = s[(2 * j) & 8191] + t[(2 * j + 1) & 8191];
    eb = eb > 0.0f ? eb : 0.2f * eb;
    wb[j] = expf(eb);
    if (j < 4096) {
        float cL = s[2 * j] + t[2 * j];
        cL = cL > 0.0f ? cL : 0.2f * cL;
        float cR = s[2 * j + 1] + t[2 * j + 1];
        cR = cR > 0.0f ? cR : 0.2f * cR;
        eL[j] = expf(cL);
        eR[j] = expf(cR);
    }
    B1t[256 * 8192 + j] = 0x3F80;
#pragma unroll
    for (int f = 257; f < 272; f++) B1t[f * 8192 + j] = 0;
}

// ---- k4: B2t[f][j] = wb[j] * B1t[f][j]
__global__ __launch_bounds__(256) void k_b2(const unsigned short* __restrict__ B1t,
                                            const float* __restrict__ wb,
                                            unsigned short* __restrict__ B2t) {
    int j = blockIdx.x * 256 + threadIdx.x;
    int f = blockIdx.y;
    B2t[f * 8192 + j] = f2bf(wb[j] * bf2f(B1t[f * 8192 + j]));
}

// ---- k5: masked GEMM, LDS-free register streaming.
// Wave = 32 rows x (144 or 128) cols x K=2048. Fragments loaded straight from
// global in MFMA layout (fully line-coalesced: 4 lanes/row x 16B = 64B line).
// A streams from HBM once; B is L2-resident. Depth-1 register prefetch, no
// barriers. K-split q in {0..3}: exactly 2 atomic contributors per output
// element (commutative f32 add -> bit-deterministic).
static __device__ __forceinline__ bf16x8 cvt01(int4 a, int4 b) {
    bf16x8 r;
    r[0] = a.x ? (short)0x3F80 : (short)0; r[1] = a.y ? (short)0x3F80 : (short)0;
    r[2] = a.z ? (short)0x3F80 : (short)0; r[3] = a.w ? (short)0x3F80 : (short)0;
    r[4] = b.x ? (short)0x3F80 : (short)0; r[5] = b.y ? (short)0x3F80 : (short)0;
    r[6] = b.z ? (short)0x3F80 : (short)0; r[7] = b.w ? (short)0x3F80 : (short)0;
    return r;
}

template <int NT>
static __device__ __forceinline__ void mg_wave(const int* __restrict__ ap,
                                               const unsigned short* __restrict__ bp,
                                               float* __restrict__ outp, int ln) {
    const long AH = 16l * 8192;   // +16 rows, in ints
    f32x4 acc[2][NT];
#pragma unroll
    for (int i = 0; i < 2; i++)
#pragma unroll
        for (int j = 0; j < NT; j++) acc[i][j] = (f32x4)0.0f;

    int4 al0 = *(const int4*)(ap), al1 = *(const int4*)(ap + 4);
    int4 ah0 = *(const int4*)(ap + AH), ah1 = *(const int4*)(ap + AH + 4);
    bf16x8 bc[NT];
#pragma unroll
    for (int nt = 0; nt < NT; nt++) bc[nt] = *(const bf16x8*)(bp + (long)nt * 16 * 8192);

#pragma unroll 1
    for (int k = 0; k < 64; k++) {
        int4 nl0, nl1, nh0, nh1;
        bf16x8 bn[NT];
        if (k < 63) {   // prefetch next K=32 slab into regs
            const int* a2 = ap + (k + 1) * 32;
            nl0 = *(const int4*)(a2);
            nl1 = *(const int4*)(a2 + 4);
            nh0 = *(const int4*)(a2 + AH);
            nh1 = *(const int4*)(a2 + AH + 4);
            const unsigned short* b2 = bp + (k + 1) * 32;
#pragma unroll
            for (int nt = 0; nt < NT; nt++)
                bn[nt] = *(const bf16x8*)(b2 + (long)nt * 16 * 8192);
        }
        bf16x8 afl = cvt01(al0, al1);
        bf16x8 afh = cvt01(ah0, ah1);
#pragma unroll
        for (int nt = 0; nt < NT; nt++) {
            acc[0][nt] = __builtin_amdgcn_mfma_f32_16x16x32_bf16(afl, bc[nt], acc[0][nt], 0, 0, 0);
            acc[1][nt] = __builtin_amdgcn_mfma_f32_16x16x32_bf16(afh, bc[nt], acc[1][nt], 0, 0, 0);
        }
        if (k < 63) {
            al0 = nl0; al1 = nl1; ah0 = nh0; ah1 = nh1;
#pragma unroll
            for (int nt = 0; nt < NT; nt++) bc[nt] = bn[nt];
        }
    }
    int lr = ln & 15, lrow = (ln >> 4) * 4;
#pragma unroll
    for (int mt = 0; mt < 2; mt++)
#pragma unroll
        for (int nt = 0; nt < NT; nt++)
#pragma unroll
            for (int r = 0; r < 4; r++)
                unsafeAtomicAdd(&outp[(long)(mt * 16 + lrow + r) * 272 + nt * 16 + lr],
                                acc[mt][nt][r]);
}

__global__ __launch_bounds__(256, 2) void k_mgemm(const int* __restrict__ sup,
                                                  const unsigned short* __restrict__ B1t,
                                                  const unsigned short* __restrict__ B2t,
                                                  float* __restrict__ TL, float* __restrict__ TR,
                                                  float* __restrict__ TB0, float* __restrict__ TB1) {
    int wv = threadIdx.x >> 6, ln = threadIdx.x & 63;
    int strip = blockIdx.x * 2 + (wv >> 1);   // 0..255 (32-row strip)
    int c = wv & 1;                           // col split: 0 -> cols 0..143, 1 -> 144..271
    int q = blockIdx.y;                       // K window q*2048
    bool topv = strip < 128;
    long m0 = (long)strip * 32;
    const unsigned short* Bt = topv ? B1t : B2t;
    float* out = topv ? (q < 2 ? TL : TR) : (q < 2 ? TB0 : TB1);
    long outr0 = topv ? m0 : m0 - 4096;
    long K0 = (long)q * 2048;
    int n0 = c ? 144 : 0;

    const int* ap = sup + (m0 + (ln & 15)) * 8192 + K0 + (ln >> 4) * 8;
    const unsigned short* bp = Bt + (long)(n0 + (ln & 15)) * 8192 + K0 + (ln >> 4) * 8;
    float* op = out + outr0 * 272 + n0;

    if (c == 0) mg_wave<9>(ap, bp, op, ln);
    else        mg_wave<8>(ap, bp, op, ln);
}

// ---- k6: combine + elu
__global__ __launch_bounds__(256) void k_out(const float* __restrict__ TL,
                                             const float* __restrict__ TR,
                                             const float* __restrict__ TB0,
                                             const float* __restrict__ TB1,
                                             const float* __restrict__ eL,
                                             const float* __restrict__ eR,
                                             float* __restrict__ outp) {
    int i = blockIdx.x, f = threadIdx.x;
    float num, den;
    if (i < 4096) {
        float el = eL[i], er = eR[i];
        den = el * TL[i * 272 + 256] + er * TR[i * 272 + 256];
        num = el * TL[i * 272 + f] + er * TR[i * 272 + f];
    } else {
        int ii = i - 4096;
        den = TB0[ii * 272 + 256] + TB1[ii * 272 + 256];
        num = TB0[ii * 272 + f] + TB1[ii * 272 + f];
    }
    float r = num / den;
    outp[i * 256 + f] = r > 0.0f ? r : expm1f(r);
}

extern "C" void kernel_launch(void* const* d_in, const int* in_sizes, int n_in,
                              void* d_out, int out_size, void* d_ws, size_t ws_size,
                              hipStream_t stream) {
    (void)in_sizes; (void)n_in; (void)out_size; (void)ws_size;
    const float* x = (const float*)d_in[0];
    const int* sup = (const int*)d_in[1];
    const float* W = (const float*)d_in[2];
    const float* a = (const float*)d_in[3];
    float* outp = (float*)d_out;

    char* ws = (char*)d_ws;
    size_t off = 0;
    auto alloc = [&](size_t bytes) -> void* {
        void* p = ws + off;
        off += (bytes + 255) & ~(size_t)255;
        return p;
    };
    unsigned short* xb  = (unsigned short*)alloc(8192 * 512 * 2);
    unsigned short* Wbt = (unsigned short*)alloc(256 * 512 * 2);
    unsigned short* h   = (unsigned short*)alloc(8192 * 256 * 2);
    unsigned short* B1t = (unsigned short*)alloc(272 * 8192 * 2);
    unsigned short* B2t = (unsigned short*)alloc(272 * 8192 * 2);
    float* s   = (float*)alloc(8192 * 4);
    float* t   = (float*)alloc(8192 * 4);
    float* wb  = (float*)alloc(8192 * 4);
    float* eL  = (float*)alloc(4096 * 4);
    float* eR  = (float*)alloc(4096 * 4);
    float* TL  = (float*)alloc(4096 * 272 * 4);
    float* TR  = (float*)alloc(4096 * 272 * 4);
    float* TB0 = (float*)alloc(4096 * 272 * 4);
    float* TB1 = (float*)alloc(4096 * 272 * 4);

    // zero the four contiguous accumulators (k_mgemm atomically adds into them)
    hipMemsetAsync(TL, 0, (size_t)4 * 4096 * 272 * 4, stream);

    k_cvt_x<<<4096, 256, 0, stream>>>(x, xb);
    k_cvt_w<<<512, 256, 0, stream>>>(W, Wbt);
    k_gemm_h<<<dim3(64, 4), 256, 0, stream>>>(xb, Wbt, h, B1t);
    k_st<<<2048, 256, 0, stream>>>(h, a, s, t);
    k_weights<<<32, 256, 0, stream>>>(s, t, wb, eL, eR, B1t);
    k_b2<<<dim3(32, 272), 256, 0, stream>>>(B1t, wb, B2t);
    k_mgemm<<<dim3(128, 4), 256, 0, stream>>>(sup, B1t, B2t, TL, TR, TB0, TB1);
    k_out<<<8192, 256, 0, stream>>>(TL, TR, TB0, TB1, eL, eR, outp);
}

// Round 4
// 212.035 us; speedup vs baseline: 1.2500x; 1.2500x over previous
//
#include <hip/hip_runtime.h>

// GraphAttentionLayer: x(8192,512) f32, support(8192,8192) i32{0,1},
// W(512,256) f32, a(512,1) f32  ->  out(8192,256) f32
//
// Decomposition (softmax shift cancels in numerator/denominator):
//   h = x@W (bf16 MFMA)
//   s = h@a1, t = h@a2, u = s+t
//   top rows i<4096 : out = elu((eL*TL + eR*TR)/(eL*TL[256] + eR*TR[256]))
//   bot rows i>=4096: out = elu(TB/TB[256]),  TB = sup[4096:, :] @ (wb .* [h|1])

typedef short bf16x8 __attribute__((ext_vector_type(8)));
typedef float f32x4 __attribute__((ext_vector_type(4)));

static __device__ __forceinline__ unsigned short f2bf(float f) {
    unsigned int u = __builtin_bit_cast(unsigned int, f);
    unsigned int r = (u + 0x7FFFu + ((u >> 16) & 1u)) >> 16;
    return (unsigned short)r;
}
static __device__ __forceinline__ float bf2f(unsigned short s) {
    unsigned int u = ((unsigned int)s) << 16;
    return __builtin_bit_cast(float, u);
}

// ---- k1a: x f32 -> bf16 row-major [8192][512]
__global__ __launch_bounds__(256) void k_cvt_x(const float* __restrict__ x,
                                               unsigned short* __restrict__ xb) {
    int i = (blockIdx.x * 256 + threadIdx.x) * 4;
    float4 v = *(const float4*)(x + i);
    ushort4 o = make_ushort4(f2bf(v.x), f2bf(v.y), f2bf(v.z), f2bf(v.w));
    *(ushort4*)(xb + i) = o;
}

// ---- k1b: W [512][256] f32 -> Wbt [256][512] bf16 (n-major, k-contiguous)
__global__ __launch_bounds__(256) void k_cvt_w(const float* __restrict__ W,
                                               unsigned short* __restrict__ Wbt) {
    int idx = blockIdx.x * 256 + threadIdx.x;
    int n = idx >> 9, k = idx & 511;
    Wbt[idx] = f2bf(W[k * 256 + n]);
}

// ---- k2: h = xb @ Wbt^T. Writes h row-major bf16 AND B1t [272][8192] rows 0..255.
__global__ __launch_bounds__(256) void k_gemm_h(const unsigned short* __restrict__ xb,
                                                const unsigned short* __restrict__ Wbt,
                                                unsigned short* __restrict__ h,
                                                unsigned short* __restrict__ B1t) {
    __shared__ unsigned short Asm[128][72];
    __shared__ unsigned short Bsm[64][72];
    int tid = threadIdx.x;
    int wv = tid >> 6, ln = tid & 63;
    int m0 = blockIdx.x * 128, n0 = blockIdx.y * 64;

    f32x4 acc[2][4];
#pragma unroll
    for (int i = 0; i < 2; i++)
#pragma unroll
        for (int j = 0; j < 4; j++) acc[i][j] = (f32x4)0.0f;

    for (int k0 = 0; k0 < 512; k0 += 64) {
        {
            int r = tid >> 1, c = (tid & 1) * 32;
            const unsigned short* src = xb + (m0 + r) * 512 + k0 + c;
            *(bf16x8*)&Asm[r][c]      = *(const bf16x8*)(src);
            *(bf16x8*)&Asm[r][c + 8]  = *(const bf16x8*)(src + 8);
            *(bf16x8*)&Asm[r][c + 16] = *(const bf16x8*)(src + 16);
            *(bf16x8*)&Asm[r][c + 24] = *(const bf16x8*)(src + 24);
        }
        {
            int r = tid >> 2, c = (tid & 3) * 16;
            const unsigned short* src = Wbt + (n0 + r) * 512 + k0 + c;
            *(bf16x8*)&Bsm[r][c]     = *(const bf16x8*)(src);
            *(bf16x8*)&Bsm[r][c + 8] = *(const bf16x8*)(src + 8);
        }
        __syncthreads();
        int lr = ln & 15, lk = (ln >> 4) * 8;
#pragma unroll
        for (int ks = 0; ks < 2; ks++) {
            int kk = ks * 32 + lk;
            bf16x8 a0 = *(const bf16x8*)&Asm[wv * 32 + lr][kk];
            bf16x8 a1 = *(const bf16x8*)&Asm[wv * 32 + 16 + lr][kk];
#pragma unroll
            for (int nt = 0; nt < 4; nt++) {
                bf16x8 b = *(const bf16x8*)&Bsm[nt * 16 + lr][kk];
                acc[0][nt] = __builtin_amdgcn_mfma_f32_16x16x32_bf16(a0, b, acc[0][nt], 0, 0, 0);
                acc[1][nt] = __builtin_amdgcn_mfma_f32_16x16x32_bf16(a1, b, acc[1][nt], 0, 0, 0);
            }
        }
        __syncthreads();
    }
    int lr = ln & 15, lrow = (ln >> 4) * 4;
#pragma unroll
    for (int mt = 0; mt < 2; mt++) {
#pragma unroll
        for (int nt = 0; nt < 4; nt++) {
            int mg = m0 + wv * 32 + mt * 16 + lrow;
            int ng = n0 + nt * 16 + lr;
            ushort4 tb = make_ushort4(f2bf(acc[mt][nt][0]), f2bf(acc[mt][nt][1]),
                                      f2bf(acc[mt][nt][2]), f2bf(acc[mt][nt][3]));
            h[(mg + 0) * 256 + ng] = tb.x;
            h[(mg + 1) * 256 + ng] = tb.y;
            h[(mg + 2) * 256 + ng] = tb.z;
            h[(mg + 3) * 256 + ng] = tb.w;
            *(ushort4*)&B1t[ng * 8192 + mg] = tb;
        }
    }
}

// ---- k3: s[j], t[j]
__global__ __launch_bounds__(256) void k_st(const unsigned short* __restrict__ h,
                                            const float* __restrict__ a,
                                            float* __restrict__ s, float* __restrict__ t) {
    int wv = threadIdx.x >> 6, ln = threadIdx.x & 63;
    int j = blockIdx.x * 4 + wv;
    ushort4 hv = *(const ushort4*)(h + j * 256 + ln * 4);
    float4 a1 = *(const float4*)(a + ln * 4);
    float4 a2 = *(const float4*)(a + 256 + ln * 4);
    float s_ = bf2f(hv.x) * a1.x + bf2f(hv.y) * a1.y + bf2f(hv.z) * a1.z + bf2f(hv.w) * a1.w;
    float t_ = bf2f(hv.x) * a2.x + bf2f(hv.y) * a2.y + bf2f(hv.z) * a2.z + bf2f(hv.w) * a2.w;
#pragma unroll
    for (int off = 32; off; off >>= 1) {
        s_ += __shfl_down(s_, off);
        t_ += __shfl_down(t_, off);
    }
    if (ln == 0) { s[j] = s_; t[j] = t_; }
}

// ---- k3b: wb / eL / eR; fill B1t aux rows (256 = ones, 257..271 = 0)
__global__ __launch_bounds__(256) void k_weights(const float* __restrict__ s,
                                                 const float* __restrict__ t,
                                                 float* __restrict__ wb,
                                                 float* __restrict__ eL,
                                                 float* __restrict__ eR,
                                                 unsigned short* __restrict__ B1t) {
    int j = blockIdx.x * 256 + threadIdx.x;
    float eb = s[(2 * j) & 8191] + t[(2 * j + 1) & 8191];
    eb = eb > 0.0f ? eb : 0.2f * eb;
    wb[j] = expf(eb);
    if (j < 4096) {
        float cL = s[2 * j] + t[2 * j];
        cL = cL > 0.0f ? cL : 0.2f * cL;
        float cR = s[2 * j + 1] + t[2 * j + 1];
        cR = cR > 0.0f ? cR : 0.2f * cR;
        eL[j] = expf(cL);
        eR[j] = expf(cR);
    }
    B1t[256 * 8192 + j] = 0x3F80;
#pragma unroll
    for (int f = 257; f < 272; f++) B1t[f * 8192 + j] = 0;
}

// ---- k4: B2t[f][j] = wb[j] * B1t[f][j]
__global__ __launch_bounds__(256) void k_b2(const unsigned short* __restrict__ B1t,
                                            const float* __restrict__ wb,
                                            unsigned short* __restrict__ B2t) {
    int j = blockIdx.x * 256 + threadIdx.x;
    int f = blockIdx.y;
    B2t[f * 8192 + j] = f2bf(wb[j] * bf2f(B1t[f * 8192 + j]));
}

// ---- k5: masked GEMM v4.
// Block = 32 rows x 272 cols x K=2048 (q-window). 4 waves split the 17
// n-fragments 5/4/4/4 (acc <= 40 VGPR). A (HBM stream) staged via
// regs->LDS double-buffer, stride-72 pad (2-way conflict = free), one
// barrier/iter. B fragments read directly from global (L2/L3-resident),
// no persistent B registers (round-3 spill fix). 1024 blocks = 4/CU.
// q in {0..3}: exactly 2 atomic f32 contributors per output element
// (commutative -> bit-deterministic).
static __device__ __forceinline__ bf16x8 cvt01(int4 a, int4 b) {
    bf16x8 r;
    r[0] = a.x ? (short)0x3F80 : (short)0; r[1] = a.y ? (short)0x3F80 : (short)0;
    r[2] = a.z ? (short)0x3F80 : (short)0; r[3] = a.w ? (short)0x3F80 : (short)0;
    r[4] = b.x ? (short)0x3F80 : (short)0; r[5] = b.y ? (short)0x3F80 : (short)0;
    r[6] = b.z ? (short)0x3F80 : (short)0; r[7] = b.w ? (short)0x3F80 : (short)0;
    return r;
}

template <int NF>
static __device__ __forceinline__ void mg_body(unsigned short* __restrict__ As,
                                               const int* __restrict__ asrc,
                                               int arow, int acx,
                                               const unsigned short* __restrict__ bp,
                                               float* __restrict__ op, int ln) {
    f32x4 acc[2][NF];
#pragma unroll
    for (int i = 0; i < 2; i++)
#pragma unroll
        for (int j = 0; j < NF; j++) acc[i][j] = (f32x4)0.0f;

    // prologue: stage iter 0 into buf 0
    {
        int4 a0 = *(const int4*)(asrc);
        int4 a1 = *(const int4*)(asrc + 4);
        *(bf16x8*)&As[arow * 72 + acx] = cvt01(a0, a1);
    }
    int r0 = (ln & 15), r1 = 16 + (ln & 15), lk = (ln >> 4) * 8;

#pragma unroll 1
    for (int it = 0; it < 32; ++it) {
        __syncthreads();
        int4 na0, na1;
        if (it < 31) {                       // issue next A slab (HBM) early
            const int* a2 = asrc + (it + 1) * 64;
            na0 = *(const int4*)(a2);
            na1 = *(const int4*)(a2 + 4);
        }
        int base = (it & 1) * 32 * 72;
#pragma unroll
        for (int kh = 0; kh < 2; kh++) {
            bf16x8 af0 = *(const bf16x8*)&As[base + r0 * 72 + kh * 32 + lk];
            bf16x8 af1 = *(const bf16x8*)&As[base + r1 * 72 + kh * 32 + lk];
#pragma unroll
            for (int f = 0; f < NF; f++) {
                bf16x8 bv = *(const bf16x8*)(bp + (long)f * 131072 + it * 64 + kh * 32);
                acc[0][f] = __builtin_amdgcn_mfma_f32_16x16x32_bf16(af0, bv, acc[0][f], 0, 0, 0);
                acc[1][f] = __builtin_amdgcn_mfma_f32_16x16x32_bf16(af1, bv, acc[1][f], 0, 0, 0);
            }
        }
        if (it < 31) {                       // write next slab to other buffer
            int nb = ((it & 1) ^ 1) * 32 * 72;
            *(bf16x8*)&As[nb + arow * 72 + acx] = cvt01(na0, na1);
        }
    }
    int lr = ln & 15, lrow = (ln >> 4) * 4;
#pragma unroll
    for (int mf = 0; mf < 2; mf++)
#pragma unroll
        for (int f = 0; f < NF; f++)
#pragma unroll
            for (int r = 0; r < 4; r++)
                unsafeAtomicAdd(&op[(long)(mf * 16 + lrow + r) * 272 + f * 16 + lr],
                                acc[mf][f][r]);
}

__global__ __launch_bounds__(256, 4) void k_mgemm(const int* __restrict__ sup,
                                                  const unsigned short* __restrict__ B1t,
                                                  const unsigned short* __restrict__ B2t,
                                                  float* __restrict__ TL, float* __restrict__ TR,
                                                  float* __restrict__ TB0, float* __restrict__ TB1) {
    __shared__ unsigned short Asm[2 * 32 * 72];   // 9216 B
    int tid = threadIdx.x;
    int wv = tid >> 6, ln = tid & 63;

    // XCD-aware remap: pin one q (K-window) per XCD so its 2.2 MB B window
    // stays L2-resident. bijection [0,1024) -> (strip 0..255, q 0..3).
    int bid = blockIdx.x + (blockIdx.y << 8);
    int xcd = bid & 7;
    int idx = bid >> 3;           // 0..127
    int q = xcd >> 1;             // 0..3
    int strip = (idx << 1) | (xcd & 1);   // 0..255

    bool topv = strip < 128;
    long m0 = (long)strip * 32;
    const unsigned short* Bt = topv ? B1t : B2t;
    float* out = topv ? ((q < 2) ? TL : TR) : ((q < 2) ? TB0 : TB1);
    long outr0 = topv ? m0 : m0 - 4096;
    long K0 = (long)q * 2048;
    int n0 = wv ? (4 * wv + 1) * 16 : 0;   // 0, 80, 144, 208

    int arow = tid >> 3, acx = (tid & 7) * 8;
    const int* asrc = sup + (m0 + arow) * 8192 + K0 + acx;
    const unsigned short* bp = Bt + (long)(n0 + (ln & 15)) * 8192 + K0 + (ln >> 4) * 8;
    float* op = out + outr0 * 272 + n0;

    if (wv == 0) mg_body<5>(Asm, asrc, arow, acx, bp, op, ln);
    else         mg_body<4>(Asm, asrc, arow, acx, bp, op, ln);
}

// ---- k6: combine + elu
__global__ __launch_bounds__(256) void k_out(const float* __restrict__ TL,
                                             const float* __restrict__ TR,
                                             const float* __restrict__ TB0,
                                             const float* __restrict__ TB1,
                                             const float* __restrict__ eL,
                                             const float* __restrict__ eR,
                                             float* __restrict__ outp) {
    int i = blockIdx.x, f = threadIdx.x;
    float num, den;
    if (i < 4096) {
        float el = eL[i], er = eR[i];
        den = el * TL[i * 272 + 256] + er * TR[i * 272 + 256];
        num = el * TL[i * 272 + f] + er * TR[i * 272 + f];
    } else {
        int ii = i - 4096;
        den = TB0[ii * 272 + 256] + TB1[ii * 272 + 256];
        num = TB0[ii * 272 + f] + TB1[ii * 272 + f];
    }
    float r = num / den;
    outp[i * 256 + f] = r > 0.0f ? r : expm1f(r);
}

extern "C" void kernel_launch(void* const* d_in, const int* in_sizes, int n_in,
                              void* d_out, int out_size, void* d_ws, size_t ws_size,
                              hipStream_t stream) {
    (void)in_sizes; (void)n_in; (void)out_size; (void)ws_size;
    const float* x = (const float*)d_in[0];
    const int* sup = (const int*)d_in[1];
    const float* W = (const float*)d_in[2];
    const float* a = (const float*)d_in[3];
    float* outp = (float*)d_out;

    char* ws = (char*)d_ws;
    size_t off = 0;
    auto alloc = [&](size_t bytes) -> void* {
        void* p = ws + off;
        off += (bytes + 255) & ~(size_t)255;
        return p;
    };
    unsigned short* xb  = (unsigned short*)alloc(8192 * 512 * 2);
    unsigned short* Wbt = (unsigned short*)alloc(256 * 512 * 2);
    unsigned short* h   = (unsigned short*)alloc(8192 * 256 * 2);
    unsigned short* B1t = (unsigned short*)alloc(272 * 8192 * 2);
    unsigned short* B2t = (unsigned short*)alloc(272 * 8192 * 2);
    float* s   = (float*)alloc(8192 * 4);
    float* t   = (float*)alloc(8192 * 4);
    float* wb  = (float*)alloc(8192 * 4);
    float* eL  = (float*)alloc(4096 * 4);
    float* eR  = (float*)alloc(4096 * 4);
    float* TL  = (float*)alloc(4096 * 272 * 4);
    float* TR  = (float*)alloc(4096 * 272 * 4);
    float* TB0 = (float*)alloc(4096 * 272 * 4);
    float* TB1 = (float*)alloc(4096 * 272 * 4);

    // zero the four contiguous accumulators (k_mgemm atomically adds into them)
    hipMemsetAsync(TL, 0, (size_t)4 * 4096 * 272 * 4, stream);

    k_cvt_x<<<4096, 256, 0, stream>>>(x, xb);
    k_cvt_w<<<512, 256, 0, stream>>>(W, Wbt);
    k_gemm_h<<<dim3(64, 4), 256, 0, stream>>>(xb, Wbt, h, B1t);
    k_st<<<2048, 256, 0, stream>>>(h, a, s, t);
    k_weights<<<32, 256, 0, stream>>>(s, t, wb, eL, eR, B1t);
    k_b2<<<dim3(32, 272), 256, 0, stream>>>(B1t, wb, B2t);
    k_mgemm<<<dim3(256, 4), 256, 0, stream>>>(sup, B1t, B2t, TL, TR, TB0, TB1);
    k_out<<<8192, 256, 0, stream>>>(TL, TR, TB0, TB1, eL, eR, outp);
}

// Round 5
// 186.485 us; speedup vs baseline: 1.4212x; 1.1370x over previous
//
#include <hip/hip_runtime.h>

// GraphAttentionLayer: x(8192,512) f32, support(8192,8192) i32{0,1},
// W(512,256) f32, a(512,1) f32  ->  out(8192,256) f32
//
// Decomposition (softmax shift cancels in numerator/denominator):
//   h = x@W (bf16 MFMA)
//   s = h@a1, t = h@a2
//   top rows i<4096 : out = elu((eL*TL + eR*TR)/(eL*TL[256] + eR*TR[256]))
//   bot rows i>=4096: out = elu(TB/TB[256]),  TB = sup[4096:, :] @ (wb .* [h|1])
//
// k_mgemm v5: A(support) -> direct global->register MFMA fragments, depth-2
// pipeline (2-slot slack covers HBM latency). B -> LDS shared by 4 M-split
// waves, staged via global_load_lds with pre-swizzled source, raw s_barrier
// + counted vmcnt(2) (loads stay in flight across barriers). K-split q=0..7
// (one q per XCD, B window L2-resident), partials to P[8] - no atomics.

typedef short bf16x8 __attribute__((ext_vector_type(8)));
typedef float f32x4 __attribute__((ext_vector_type(4)));

static __device__ __forceinline__ unsigned short f2bf(float f) {
    unsigned int u = __builtin_bit_cast(unsigned int, f);
    unsigned int r = (u + 0x7FFFu + ((u >> 16) & 1u)) >> 16;
    return (unsigned short)r;
}
static __device__ __forceinline__ float bf2f(unsigned short s) {
    unsigned int u = ((unsigned int)s) << 16;
    return __builtin_bit_cast(float, u);
}
static __device__ __forceinline__ void glds16(const unsigned short* g, unsigned short* l) {
    __builtin_amdgcn_global_load_lds(
        (const __attribute__((address_space(1))) unsigned int*)(g),
        (__attribute__((address_space(3))) unsigned int*)(l), 16, 0, 0);
}

// ---- k1a: x f32 -> bf16 row-major [8192][512]
__global__ __launch_bounds__(256) void k_cvt_x(const float* __restrict__ x,
                                               unsigned short* __restrict__ xb) {
    int i = (blockIdx.x * 256 + threadIdx.x) * 4;
    float4 v = *(const float4*)(x + i);
    ushort4 o = make_ushort4(f2bf(v.x), f2bf(v.y), f2bf(v.z), f2bf(v.w));
    *(ushort4*)(xb + i) = o;
}

// ---- k1b: W [512][256] f32 -> Wbt [256][512] bf16 (n-major, k-contiguous)
__global__ __launch_bounds__(256) void k_cvt_w(const float* __restrict__ W,
                                               unsigned short* __restrict__ Wbt) {
    int idx = blockIdx.x * 256 + threadIdx.x;
    int n = idx >> 9, k = idx & 511;
    Wbt[idx] = f2bf(W[k * 256 + n]);
}

// ---- k2: h = xb @ Wbt^T. Writes h row-major bf16 AND B1t [272][8192] rows 0..255.
__global__ __launch_bounds__(256) void k_gemm_h(const unsigned short* __restrict__ xb,
                                                const unsigned short* __restrict__ Wbt,
                                                unsigned short* __restrict__ h,
                                                unsigned short* __restrict__ B1t) {
    __shared__ unsigned short Asm[128][72];
    __shared__ unsigned short Bsm[64][72];
    int tid = threadIdx.x;
    int wv = tid >> 6, ln = tid & 63;
    int m0 = blockIdx.x * 128, n0 = blockIdx.y * 64;

    f32x4 acc[2][4];
#pragma unroll
    for (int i = 0; i < 2; i++)
#pragma unroll
        for (int j = 0; j < 4; j++) acc[i][j] = (f32x4)0.0f;

    for (int k0 = 0; k0 < 512; k0 += 64) {
        {
            int r = tid >> 1, c = (tid & 1) * 32;
            const unsigned short* src = xb + (m0 + r) * 512 + k0 + c;
            *(bf16x8*)&Asm[r][c]      = *(const bf16x8*)(src);
            *(bf16x8*)&Asm[r][c + 8]  = *(const bf16x8*)(src + 8);
            *(bf16x8*)&Asm[r][c + 16] = *(const bf16x8*)(src + 16);
            *(bf16x8*)&Asm[r][c + 24] = *(const bf16x8*)(src + 24);
        }
        {
            int r = tid >> 2, c = (tid & 3) * 16;
            const unsigned short* src = Wbt + (n0 + r) * 512 + k0 + c;
            *(bf16x8*)&Bsm[r][c]     = *(const bf16x8*)(src);
            *(bf16x8*)&Bsm[r][c + 8] = *(const bf16x8*)(src + 8);
        }
        __syncthreads();
        int lr = ln & 15, lk = (ln >> 4) * 8;
#pragma unroll
        for (int ks = 0; ks < 2; ks++) {
            int kk = ks * 32 + lk;
            bf16x8 a0 = *(const bf16x8*)&Asm[wv * 32 + lr][kk];
            bf16x8 a1 = *(const bf16x8*)&Asm[wv * 32 + 16 + lr][kk];
#pragma unroll
            for (int nt = 0; nt < 4; nt++) {
                bf16x8 b = *(const bf16x8*)&Bsm[nt * 16 + lr][kk];
                acc[0][nt] = __builtin_amdgcn_mfma_f32_16x16x32_bf16(a0, b, acc[0][nt], 0, 0, 0);
                acc[1][nt] = __builtin_amdgcn_mfma_f32_16x16x32_bf16(a1, b, acc[1][nt], 0, 0, 0);
            }
        }
        __syncthreads();
    }
    int lr = ln & 15, lrow = (ln >> 4) * 4;
#pragma unroll
    for (int mt = 0; mt < 2; mt++) {
#pragma unroll
        for (int nt = 0; nt < 4; nt++) {
            int mg = m0 + wv * 32 + mt * 16 + lrow;
            int ng = n0 + nt * 16 + lr;
            ushort4 tb = make_ushort4(f2bf(acc[mt][nt][0]), f2bf(acc[mt][nt][1]),
                                      f2bf(acc[mt][nt][2]), f2bf(acc[mt][nt][3]));
            h[(mg + 0) * 256 + ng] = tb.x;
            h[(mg + 1) * 256 + ng] = tb.y;
            h[(mg + 2) * 256 + ng] = tb.z;
            h[(mg + 3) * 256 + ng] = tb.w;
            *(ushort4*)&B1t[ng * 8192 + mg] = tb;
        }
    }
}

// ---- k3: s[j], t[j]
__global__ __launch_bounds__(256) void k_st(const unsigned short* __restrict__ h,
                                            const float* __restrict__ a,
                                            float* __restrict__ s, float* __restrict__ t) {
    int wv = threadIdx.x >> 6, ln = threadIdx.x & 63;
    int j = blockIdx.x * 4 + wv;
    ushort4 hv = *(const ushort4*)(h + j * 256 + ln * 4);
    float4 a1 = *(const float4*)(a + ln * 4);
    float4 a2 = *(const float4*)(a + 256 + ln * 4);
    float s_ = bf2f(hv.x) * a1.x + bf2f(hv.y) * a1.y + bf2f(hv.z) * a1.z + bf2f(hv.w) * a1.w;
    float t_ = bf2f(hv.x) * a2.x + bf2f(hv.y) * a2.y + bf2f(hv.z) * a2.z + bf2f(hv.w) * a2.w;
#pragma unroll
    for (int off = 32; off; off >>= 1) {
        s_ += __shfl_down(s_, off);
        t_ += __shfl_down(t_, off);
    }
    if (ln == 0) { s[j] = s_; t[j] = t_; }
}

// ---- k3b: wb / eL / eR; fill B1t aux rows (256 = ones, 257..271 = 0)
__global__ __launch_bounds__(256) void k_weights(const float* __restrict__ s,
                                                 const float* __restrict__ t,
                                                 float* __restrict__ wb,
                                                 float* __restrict__ eL,
                                                 float* __restrict__ eR,
                                                 unsigned short* __restrict__ B1t) {
    int j = blockIdx.x * 256 + threadIdx.x;
    float eb = s[(2 * j) & 8191] + t[(2 * j + 1) & 8191];
    eb = eb > 0.0f ? eb : 0.2f * eb;
    wb[j] = expf(eb);
    if (j < 4096) {
        float cL = s[2 * j] + t[2 * j];
        cL = cL > 0.0f ? cL : 0.2f * cL;
        float cR = s[2 * j + 1] + t[2 * j + 1];
        cR = cR > 0.0f ? cR : 0.2f * cR;
        eL[j] = expf(cL);
        eR[j] = expf(cR);
    }
    B1t[256 * 8192 + j] = 0x3F80;
#pragma unroll
    for (int f = 257; f < 272; f++) B1t[f * 8192 + j] = 0;
}

// ---- k4: B2t[f][j] = wb[j] * B1t[f][j]
__global__ __launch_bounds__(256) void k_b2(const unsigned short* __restrict__ B1t,
                                            const float* __restrict__ wb,
                                            unsigned short* __restrict__ B2t) {
    int j = blockIdx.x * 256 + threadIdx.x;
    int f = blockIdx.y;
    B2t[f * 8192 + j] = f2bf(wb[j] * bf2f(B1t[f * 8192 + j]));
}

// ---- k5: masked GEMM v5 (see header comment).
// Block: BM=64 rows (4 waves x 16) x 272 cols x K=1024 (q-window), BK=32.
static __device__ __forceinline__ bf16x8 cvt01(int4 a, int4 b) {
    bf16x8 r;
    r[0] = a.x ? (short)0x3F80 : (short)0; r[1] = a.y ? (short)0x3F80 : (short)0;
    r[2] = a.z ? (short)0x3F80 : (short)0; r[3] = a.w ? (short)0x3F80 : (short)0;
    r[4] = b.x ? (short)0x3F80 : (short)0; r[5] = b.y ? (short)0x3F80 : (short)0;
    r[6] = b.z ? (short)0x3F80 : (short)0; r[7] = b.w ? (short)0x3F80 : (short)0;
    return r;
}

__global__ __launch_bounds__(256, 4) void k_mgemm(const int* __restrict__ sup,
                                                  const unsigned short* __restrict__ B1t,
                                                  const unsigned short* __restrict__ B2t,
                                                  float* __restrict__ P) {
    __shared__ unsigned short Bsm[2 * 8704];   // 2 x 17408 B, linear (glds dest)
    int tid = threadIdx.x, wv = tid >> 6, ln = tid & 63;
    int bid = blockIdx.x;
    int q = bid & 7;                 // XCD-pinned K-window (8 XCDs)
    int strip = bid >> 3;            // 0..127
    long K0 = (long)q * 1024;
    long m0 = (long)strip * 64;
    const unsigned short* Bt = (strip < 64) ? B1t : B2t;

    // ---- B staging: 1088 16B-chunks; wave w instr i covers chunks
    // [i*256 + w*64, +64). LDS is linear; global SOURCE is pre-swizzled so the
    // fragment ds_read (XOR'd address) is ~conflict-free (rule #21).
    const unsigned short* sp0; const unsigned short* sp1;
    const unsigned short* sp2; const unsigned short* sp3;
    const unsigned short* sp4;
    int cb0, cb1, cb2, cb3, cb4;
    {
        int ch;
#define SETUP_SP(I, SP, CB) \
        ch = (I)*256 + wv*64 + ln; \
        { int row = ch >> 2, c = ch & 3; \
          CB = ((I)*256 + wv*64) * 8; \
          SP = Bt + (long)row * 8192 + K0 + ((c ^ (row & 3)) << 3); }
        SETUP_SP(0, sp0, cb0)
        SETUP_SP(1, sp1, cb1)
        SETUP_SP(2, sp2, cb2)
        SETUP_SP(3, sp3, cb3)
        ch = 1024 + ln;
        { int row = ch >> 2, c = ch & 3;
          cb4 = 1024 * 8;
          sp4 = Bt + (long)row * 8192 + K0 + ((c ^ (row & 3)) << 3); }
#undef SETUP_SP
    }

    // ---- A: direct global -> MFMA fragment. lane: row = ln&15, k-chunk = ln>>4.
    const int* ap = sup + (m0 + wv * 16 + (ln & 15)) * 8192 + K0 + (ln >> 4) * 8;

    f32x4 acc[17];
#pragma unroll
    for (int i = 0; i < 17; i++) acc[i] = (f32x4)0.0f;

    // prologue: stage B(0) (glds first so vmcnt(4) leaves only the A loads),
    // then A(0), A(1) into registers.
    {
        unsigned short* dst = Bsm;
        glds16(sp0, dst + cb0);
        glds16(sp1, dst + cb1);
        glds16(sp2, dst + cb2);
        glds16(sp3, dst + cb3);
        if (wv == 0) glds16(sp4, dst + cb4);
    }
    int4 c0 = *(const int4*)(ap);
    int4 c1 = *(const int4*)(ap + 4);
    int4 n0 = *(const int4*)(ap + 32);
    int4 n1 = *(const int4*)(ap + 36);
    int4 f0 = c0, f1 = c1;
    asm volatile("s_waitcnt vmcnt(4)" ::: "memory");
    __builtin_amdgcn_s_barrier();

    int lr = ln & 15;
    int swz16 = 16 * ((ln >> 4) ^ (ln & 3));   // XOR-swizzled k-chunk select

#pragma unroll 1
    for (int it = 0; it < 32; ++it) {
        int buf = it & 1;
        if (it < 31) {   // stage B(it+1) into other buffer (async, glds)
            unsigned short* dst = Bsm + (buf ^ 1) * 8704;
            glds16(sp0 + (it + 1) * 32, dst + cb0);
            glds16(sp1 + (it + 1) * 32, dst + cb1);
            glds16(sp2 + (it + 1) * 32, dst + cb2);
            glds16(sp3 + (it + 1) * 32, dst + cb3);
            if (wv == 0) glds16(sp4 + (it + 1) * 32, dst + cb4);
        }
        if (it < 30) {   // issue A(it+2): 2-slot register pipeline
            f0 = *(const int4*)(ap + (it + 2) * 32);
            f1 = *(const int4*)(ap + (it + 2) * 32 + 4);
        }
        bf16x8 av = cvt01(c0, c1);
        const char* base = (const char*)Bsm + buf * 17408 + 64 * lr + swz16;
#pragma unroll
        for (int f = 0; f < 17; f++) {
            bf16x8 bv = *(const bf16x8*)(base + f * 1024);
            acc[f] = __builtin_amdgcn_mfma_f32_16x16x32_bf16(av, bv, acc[f], 0, 0, 0);
        }
        c0 = n0; c1 = n1; n0 = f0; n1 = f1;
        if (it < 31) {
            // drain B-stage (and A(it+1)); keep A(it+2) in flight across barrier
            if (it < 30) asm volatile("s_waitcnt vmcnt(2)" ::: "memory");
            else         asm volatile("s_waitcnt vmcnt(0)" ::: "memory");
            __builtin_amdgcn_s_barrier();
        }
    }

    // epilogue: plain stores to this block's private partial (no atomics).
    long grow = m0 + wv * 16 + (ln >> 4) * 4;
    float* op = P + ((long)q * 8192 + grow) * 272 + lr;
#pragma unroll
    for (int f = 0; f < 17; f++)
#pragma unroll
        for (int r = 0; r < 4; r++)
            op[(long)r * 272 + f * 16] = acc[f][r];
}

// ---- k6: combine 8 partials + elu
__global__ __launch_bounds__(256) void k_out(const float* __restrict__ P,
                                             const float* __restrict__ eL,
                                             const float* __restrict__ eR,
                                             float* __restrict__ outp) {
    int i = blockIdx.x, f = threadIdx.x;
    const float* p = P + (long)i * 272;
    const long QS = 8192l * 272;
    float num, den;
    if (i < 4096) {
        float tln = 0, trn = 0, tld = 0, trd = 0;
#pragma unroll
        for (int q = 0; q < 4; q++) { tln += p[q * QS + f]; tld += p[q * QS + 256]; }
#pragma unroll
        for (int q = 4; q < 8; q++) { trn += p[q * QS + f]; trd += p[q * QS + 256]; }
        float el = eL[i], er = eR[i];
        num = el * tln + er * trn;
        den = el * tld + er * trd;
    } else {
        num = 0; den = 0;
#pragma unroll
        for (int q = 0; q < 8; q++) { num += p[q * QS + f]; den += p[q * QS + 256]; }
    }
    float r = num / den;
    outp[(long)i * 256 + f] = r > 0.0f ? r : expm1f(r);
}

extern "C" void kernel_launch(void* const* d_in, const int* in_sizes, int n_in,
                              void* d_out, int out_size, void* d_ws, size_t ws_size,
                              hipStream_t stream) {
    (void)in_sizes; (void)n_in; (void)out_size; (void)ws_size;
    const float* x = (const float*)d_in[0];
    const int* sup = (const int*)d_in[1];
    const float* W = (const float*)d_in[2];
    const float* a = (const float*)d_in[3];
    float* outp = (float*)d_out;

    char* ws = (char*)d_ws;
    size_t off = 0;
    auto alloc = [&](size_t bytes) -> void* {
        void* p = ws + off;
        off += (bytes + 255) & ~(size_t)255;
        return p;
    };
    unsigned short* xb  = (unsigned short*)alloc(8192 * 512 * 2);
    unsigned short* Wbt = (unsigned short*)alloc(256 * 512 * 2);
    unsigned short* h   = (unsigned short*)alloc(8192 * 256 * 2);
    unsigned short* B1t = (unsigned short*)alloc(272 * 8192 * 2);
    unsigned short* B2t = (unsigned short*)alloc(272 * 8192 * 2);
    float* s   = (float*)alloc(8192 * 4);
    float* t   = (float*)alloc(8192 * 4);
    float* wb  = (float*)alloc(8192 * 4);
    float* eL  = (float*)alloc(4096 * 4);
    float* eR  = (float*)alloc(4096 * 4);
    float* P   = (float*)alloc((size_t)8 * 8192 * 272 * 4);   // 71.3 MB partials

    k_cvt_x<<<4096, 256, 0, stream>>>(x, xb);
    k_cvt_w<<<512, 256, 0, stream>>>(W, Wbt);
    k_gemm_h<<<dim3(64, 4), 256, 0, stream>>>(xb, Wbt, h, B1t);
    k_st<<<2048, 256, 0, stream>>>(h, a, s, t);
    k_weights<<<32, 256, 0, stream>>>(s, t, wb, eL, eR, B1t);
    k_b2<<<dim3(32, 272), 256, 0, stream>>>(B1t, wb, B2t);
    k_mgemm<<<1024, 256, 0, stream>>>(sup, B1t, B2t, P);
    k_out<<<8192, 256, 0, stream>>>(P, eL, eR, outp);
}

// Round 6
// 171.146 us; speedup vs baseline: 1.5486x; 1.0896x over previous
//
#include <hip/hip_runtime.h>

// GraphAttentionLayer: x(8192,512) f32, support(8192,8192) i32{0,1},
// W(512,256) f32, a(512,1) f32  ->  out(8192,256) f32
//
// Decomposition (softmax shift cancels in numerator/denominator):
//   h = x@W (bf16 MFMA)
//   s = h@a1, t = h@a2
//   top rows i<4096 : out = elu((eL*TL + eR*TR)/(eL*TL[256] + eR*TR[256]))
//   bot rows i>=4096: out = elu(TB/TB[256]),  TB = sup[4096:, :] @ (wb .* [h|1])
//
// k_mgemm v6 (deep-slack pipeline): BM=128, BN=272, BK=32, K-split q=0..7
// (XCD-pinned, B window L2-resident). B -> 4 LDS buffers staged via
// global_load_lds 3 tiles ahead (~3 iters slack); A -> 3-slot register
// pipeline (2 iters slack). Counted s_waitcnt vmcnt(14) + raw s_barrier:
// loads stay in flight across barriers (T3/T4). Partials to P[8], no atomics.

typedef short bf16x8 __attribute__((ext_vector_type(8)));
typedef float f32x4 __attribute__((ext_vector_type(4)));

static __device__ __forceinline__ unsigned short f2bf(float f) {
    unsigned int u = __builtin_bit_cast(unsigned int, f);
    unsigned int r = (u + 0x7FFFu + ((u >> 16) & 1u)) >> 16;
    return (unsigned short)r;
}
static __device__ __forceinline__ float bf2f(unsigned short s) {
    unsigned int u = ((unsigned int)s) << 16;
    return __builtin_bit_cast(float, u);
}
static __device__ __forceinline__ void glds16(const unsigned short* g, unsigned short* l) {
    __builtin_amdgcn_global_load_lds(
        (const __attribute__((address_space(1))) unsigned int*)(g),
        (__attribute__((address_space(3))) unsigned int*)(l), 16, 0, 0);
}

// ---- k1a: x f32 -> bf16 row-major [8192][512]
__global__ __launch_bounds__(256) void k_cvt_x(const float* __restrict__ x,
                                               unsigned short* __restrict__ xb) {
    int i = (blockIdx.x * 256 + threadIdx.x) * 4;
    float4 v = *(const float4*)(x + i);
    ushort4 o = make_ushort4(f2bf(v.x), f2bf(v.y), f2bf(v.z), f2bf(v.w));
    *(ushort4*)(xb + i) = o;
}

// ---- k1b: W [512][256] f32 -> Wbt [256][512] bf16 (n-major, k-contiguous)
__global__ __launch_bounds__(256) void k_cvt_w(const float* __restrict__ W,
                                               unsigned short* __restrict__ Wbt) {
    int idx = blockIdx.x * 256 + threadIdx.x;
    int n = idx >> 9, k = idx & 511;
    Wbt[idx] = f2bf(W[k * 256 + n]);
}

// ---- k2: h = xb @ Wbt^T. Writes h row-major bf16 AND B1t [272][8192] rows 0..255.
__global__ __launch_bounds__(256) void k_gemm_h(const unsigned short* __restrict__ xb,
                                                const unsigned short* __restrict__ Wbt,
                                                unsigned short* __restrict__ h,
                                                unsigned short* __restrict__ B1t) {
    __shared__ unsigned short Asm[128][72];
    __shared__ unsigned short Bsm[64][72];
    int tid = threadIdx.x;
    int wv = tid >> 6, ln = tid & 63;
    int m0 = blockIdx.x * 128, n0 = blockIdx.y * 64;

    f32x4 acc[2][4];
#pragma unroll
    for (int i = 0; i < 2; i++)
#pragma unroll
        for (int j = 0; j < 4; j++) acc[i][j] = (f32x4)0.0f;

    for (int k0 = 0; k0 < 512; k0 += 64) {
        {
            int r = tid >> 1, c = (tid & 1) * 32;
            const unsigned short* src = xb + (m0 + r) * 512 + k0 + c;
            *(bf16x8*)&Asm[r][c]      = *(const bf16x8*)(src);
            *(bf16x8*)&Asm[r][c + 8]  = *(const bf16x8*)(src + 8);
            *(bf16x8*)&Asm[r][c + 16] = *(const bf16x8*)(src + 16);
            *(bf16x8*)&Asm[r][c + 24] = *(const bf16x8*)(src + 24);
        }
        {
            int r = tid >> 2, c = (tid & 3) * 16;
            const unsigned short* src = Wbt + (n0 + r) * 512 + k0 + c;
            *(bf16x8*)&Bsm[r][c]     = *(const bf16x8*)(src);
            *(bf16x8*)&Bsm[r][c + 8] = *(const bf16x8*)(src + 8);
        }
        __syncthreads();
        int lr = ln & 15, lk = (ln >> 4) * 8;
#pragma unroll
        for (int ks = 0; ks < 2; ks++) {
            int kk = ks * 32 + lk;
            bf16x8 a0 = *(const bf16x8*)&Asm[wv * 32 + lr][kk];
            bf16x8 a1 = *(const bf16x8*)&Asm[wv * 32 + 16 + lr][kk];
#pragma unroll
            for (int nt = 0; nt < 4; nt++) {
                bf16x8 b = *(const bf16x8*)&Bsm[nt * 16 + lr][kk];
                acc[0][nt] = __builtin_amdgcn_mfma_f32_16x16x32_bf16(a0, b, acc[0][nt], 0, 0, 0);
                acc[1][nt] = __builtin_amdgcn_mfma_f32_16x16x32_bf16(a1, b, acc[1][nt], 0, 0, 0);
            }
        }
        __syncthreads();
    }
    int lr = ln & 15, lrow = (ln >> 4) * 4;
#pragma unroll
    for (int mt = 0; mt < 2; mt++) {
#pragma unroll
        for (int nt = 0; nt < 4; nt++) {
            int mg = m0 + wv * 32 + mt * 16 + lrow;
            int ng = n0 + nt * 16 + lr;
            ushort4 tb = make_ushort4(f2bf(acc[mt][nt][0]), f2bf(acc[mt][nt][1]),
                                      f2bf(acc[mt][nt][2]), f2bf(acc[mt][nt][3]));
            h[(mg + 0) * 256 + ng] = tb.x;
            h[(mg + 1) * 256 + ng] = tb.y;
            h[(mg + 2) * 256 + ng] = tb.z;
            h[(mg + 3) * 256 + ng] = tb.w;
            *(ushort4*)&B1t[ng * 8192 + mg] = tb;
        }
    }
}

// ---- k3: s[j], t[j]
__global__ __launch_bounds__(256) void k_st(const unsigned short* __restrict__ h,
                                            const float* __restrict__ a,
                                            float* __restrict__ s, float* __restrict__ t) {
    int wv = threadIdx.x >> 6, ln = threadIdx.x & 63;
    int j = blockIdx.x * 4 + wv;
    ushort4 hv = *(const ushort4*)(h + j * 256 + ln * 4);
    float4 a1 = *(const float4*)(a + ln * 4);
    float4 a2 = *(const float4*)(a + 256 + ln * 4);
    float s_ = bf2f(hv.x) * a1.x + bf2f(hv.y) * a1.y + bf2f(hv.z) * a1.z + bf2f(hv.w) * a1.w;
    float t_ = bf2f(hv.x) * a2.x + bf2f(hv.y) * a2.y + bf2f(hv.z) * a2.z + bf2f(hv.w) * a2.w;
#pragma unroll
    for (int off = 32; off; off >>= 1) {
        s_ += __shfl_down(s_, off);
        t_ += __shfl_down(t_, off);
    }
    if (ln == 0) { s[j] = s_; t[j] = t_; }
}

// ---- k3b: wb / eL / eR; fill B1t aux rows (256 = ones, 257..271 = 0)
__global__ __launch_bounds__(256) void k_weights(const float* __restrict__ s,
                                                 const float* __restrict__ t,
                                                 float* __restrict__ wb,
                                                 float* __restrict__ eL,
                                                 float* __restrict__ eR,
                                                 unsigned short* __restrict__ B1t) {
    int j = blockIdx.x * 256 + threadIdx.x;
    float eb = s[(2 * j) & 8191] + t[(2 * j + 1) & 8191];
    eb = eb > 0.0f ? eb : 0.2f * eb;
    wb[j] = expf(eb);
    if (j < 4096) {
        float cL = s[2 * j] + t[2 * j];
        cL = cL > 0.0f ? cL : 0.2f * cL;
        float cR = s[2 * j + 1] + t[2 * j + 1];
        cR = cR > 0.0f ? cR : 0.2f * cR;
        eL[j] = expf(cL);
        eR[j] = expf(cR);
    }
    B1t[256 * 8192 + j] = 0x3F80;
#pragma unroll
    for (int f = 257; f < 272; f++) B1t[f * 8192 + j] = 0;
}

// ---- k4: B2t[f][j] = wb[j] * B1t[f][j]
__global__ __launch_bounds__(256) void k_b2(const unsigned short* __restrict__ B1t,
                                            const float* __restrict__ wb,
                                            unsigned short* __restrict__ B2t) {
    int j = blockIdx.x * 256 + threadIdx.x;
    int f = blockIdx.y;
    B2t[f * 8192 + j] = f2bf(wb[j] * bf2f(B1t[f * 8192 + j]));
}

// ---- k5: masked GEMM v6 (see header comment).
static __device__ __forceinline__ bf16x8 cvt01(int4 a, int4 b) {
    bf16x8 r;
    r[0] = a.x ? (short)0x3F80 : (short)0; r[1] = a.y ? (short)0x3F80 : (short)0;
    r[2] = a.z ? (short)0x3F80 : (short)0; r[3] = a.w ? (short)0x3F80 : (short)0;
    r[4] = b.x ? (short)0x3F80 : (short)0; r[5] = b.y ? (short)0x3F80 : (short)0;
    r[6] = b.z ? (short)0x3F80 : (short)0; r[7] = b.w ? (short)0x3F80 : (short)0;
    return r;
}

__global__ __launch_bounds__(256, 2) void k_mgemm(const int* __restrict__ sup,
                                                  const unsigned short* __restrict__ B1t,
                                                  const unsigned short* __restrict__ B2t,
                                                  float* __restrict__ P) {
    __shared__ unsigned short Bsm[4 * 8704];   // 4 bufs x 17408 B, linear glds dest
    int tid = threadIdx.x, wv = tid >> 6, ln = tid & 63;
    int bid = blockIdx.x;
    int q = bid & 7;                 // XCD-pinned K-window
    int strip = bid >> 3;            // 0..63
    long K0 = (long)q * 1024;
    long m0 = (long)strip * 128;
    const unsigned short* Bt = (strip < 32) ? B1t : B2t;

    // B staging: 1088 16B-chunks/tile; 5 glds per wave (5th lane-masked to
    // ln<16 so vmcnt counts stay wave-uniform). LDS linear; global source
    // pre-swizzled so the XOR'd fragment ds_read is conflict-spread (rule #21).
    const unsigned short* sp[5];
    int cb[5];
#pragma unroll
    for (int i = 0; i < 4; i++) {
        int ch = i * 256 + wv * 64 + ln;
        int row = ch >> 2, c = ch & 3;
        cb[i] = (i * 256 + wv * 64) * 8;
        sp[i] = Bt + (long)row * 8192 + K0 + ((c ^ (row & 3)) << 3);
    }
    {
        int ch = 1024 + wv * 16 + (ln & 15);
        int row = ch >> 2, c = ch & 3;
        cb[4] = (1024 + wv * 16) * 8;
        sp[4] = Bt + (long)row * 8192 + K0 + ((c ^ (row & 3)) << 3);
    }

    // A: direct global -> MFMA fragments. Wave covers 32 rows (2 frags).
    const int* ap0 = sup + (m0 + wv * 32 + (ln & 15)) * 8192 + K0 + (ln >> 4) * 8;
    const int* ap1 = ap0 + 16 * 8192;

    f32x4 acc[2][17];
#pragma unroll
    for (int i = 0; i < 2; i++)
#pragma unroll
        for (int j = 0; j < 17; j++) acc[i][j] = (f32x4)0.0f;

#define STAGE_B(T) do {                                              \
        unsigned short* dst_ = Bsm + ((T) & 3) * 8704;               \
        long ko_ = (long)(T) * 32;                                   \
        glds16(sp[0] + ko_, dst_ + cb[0]);                           \
        glds16(sp[1] + ko_, dst_ + cb[1]);                           \
        glds16(sp[2] + ko_, dst_ + cb[2]);                           \
        glds16(sp[3] + ko_, dst_ + cb[3]);                           \
        if (ln < 16) glds16(sp[4] + ko_, dst_ + cb[4]);              \
    } while (0)

    int4 c0, c1, c2, c3;      // A(it)
    int4 n0, n1, n2, n3;      // A(it+1)
    int4 g0, g1, g2, g3;      // A(it+2) in flight

    // ---- prologue: order = B0, A0, B1, A1, B2  (matches steady-state queue)
    STAGE_B(0);
    c0 = *(const int4*)(ap0); c1 = *(const int4*)(ap0 + 4);
    c2 = *(const int4*)(ap1); c3 = *(const int4*)(ap1 + 4);
    STAGE_B(1);
    n0 = *(const int4*)(ap0 + 32); n1 = *(const int4*)(ap0 + 36);
    n2 = *(const int4*)(ap1 + 32); n3 = *(const int4*)(ap1 + 36);
    STAGE_B(2);
    // keep {B1(5), A1(4), B2(5)} = 14 in flight; drain B0+A0
    asm volatile("s_waitcnt vmcnt(14)" ::: "memory");
    __builtin_amdgcn_s_barrier();

    int lr = ln & 15;
    int swz16 = 16 * ((ln >> 4) ^ (ln & 3));

#pragma unroll 1
    for (int it = 0; it < 32; ++it) {
        if (it < 30) {   // issue A(it+2)
            const int* a0 = ap0 + (it + 2) * 32;
            const int* a1 = ap1 + (it + 2) * 32;
            g0 = *(const int4*)(a0); g1 = *(const int4*)(a0 + 4);
            g2 = *(const int4*)(a1); g3 = *(const int4*)(a1 + 4);
        }
        if (it < 29) STAGE_B(it + 3);   // issue B(it+3) (3 iters of slack)

        bf16x8 av0 = cvt01(c0, c1);
        bf16x8 av1 = cvt01(c2, c3);
        const char* base = (const char*)Bsm + (it & 3) * 17408 + 64 * lr + swz16;
#pragma unroll
        for (int f = 0; f < 17; f++) {
            bf16x8 bv = *(const bf16x8*)(base + f * 1024);
            acc[0][f] = __builtin_amdgcn_mfma_f32_16x16x32_bf16(av0, bv, acc[0][f], 0, 0, 0);
            acc[1][f] = __builtin_amdgcn_mfma_f32_16x16x32_bf16(av1, bv, acc[1][f], 0, 0, 0);
        }
        c0 = n0; c1 = n1; c2 = n2; c3 = n3;
        n0 = g0; n1 = g1; n2 = g2; n3 = g3;

        // counted drain: retire exactly {B(it+1), A(it+1)}; keep newer loads
        // in flight across the barrier. Tail peels the counts.
        if (it < 29) {
            asm volatile("s_waitcnt vmcnt(14)" ::: "memory");
            __builtin_amdgcn_s_barrier();
        } else if (it == 29) {
            asm volatile("s_waitcnt vmcnt(9)" ::: "memory");
            __builtin_amdgcn_s_barrier();
        } else if (it == 30) {
            asm volatile("s_waitcnt vmcnt(0)" ::: "memory");
            __builtin_amdgcn_s_barrier();
        }
    }
#undef STAGE_B

    // epilogue: plain stores to this block's private q-partial (no atomics)
    long grow = m0 + wv * 32 + (ln >> 4) * 4;
    float* op = P + ((long)q * 8192 + grow) * 272 + lr;
#pragma unroll
    for (int mf = 0; mf < 2; mf++)
#pragma unroll
        for (int f = 0; f < 17; f++)
#pragma unroll
            for (int r = 0; r < 4; r++)
                op[(long)(mf * 16 + r) * 272 + f * 16] = acc[mf][f][r];
}

// ---- k6: combine 8 partials + elu
__global__ __launch_bounds__(256) void k_out(const float* __restrict__ P,
                                             const float* __restrict__ eL,
                                             const float* __restrict__ eR,
                                             float* __restrict__ outp) {
    int i = blockIdx.x, f = threadIdx.x;
    const float* p = P + (long)i * 272;
    const long QS = 8192l * 272;
    float num, den;
    if (i < 4096) {
        float tln = 0, trn = 0, tld = 0, trd = 0;
#pragma unroll
        for (int q = 0; q < 4; q++) { tln += p[q * QS + f]; tld += p[q * QS + 256]; }
#pragma unroll
        for (int q = 4; q < 8; q++) { trn += p[q * QS + f]; trd += p[q * QS + 256]; }
        float el = eL[i], er = eR[i];
        num = el * tln + er * trn;
        den = el * tld + er * trd;
    } else {
        num = 0; den = 0;
#pragma unroll
        for (int q = 0; q < 8; q++) { num += p[q * QS + f]; den += p[q * QS + 256]; }
    }
    float r = num / den;
    outp[(long)i * 256 + f] = r > 0.0f ? r : expm1f(r);
}

extern "C" void kernel_launch(void* const* d_in, const int* in_sizes, int n_in,
                              void* d_out, int out_size, void* d_ws, size_t ws_size,
                              hipStream_t stream) {
    (void)in_sizes; (void)n_in; (void)out_size; (void)ws_size;
    const float* x = (const float*)d_in[0];
    const int* sup = (const int*)d_in[1];
    const float* W = (const float*)d_in[2];
    const float* a = (const float*)d_in[3];
    float* outp = (float*)d_out;

    char* ws = (char*)d_ws;
    size_t off = 0;
    auto alloc = [&](size_t bytes) -> void* {
        void* p = ws + off;
        off += (bytes + 255) & ~(size_t)255;
        return p;
    };
    unsigned short* xb  = (unsigned short*)alloc(8192 * 512 * 2);
    unsigned short* Wbt = (unsigned short*)alloc(256 * 512 * 2);
    unsigned short* h   = (unsigned short*)alloc(8192 * 256 * 2);
    unsigned short* B1t = (unsigned short*)alloc(272 * 8192 * 2);
    unsigned short* B2t = (unsigned short*)alloc(272 * 8192 * 2);
    float* s   = (float*)alloc(8192 * 4);
    float* t   = (float*)alloc(8192 * 4);
    float* wb  = (float*)alloc(8192 * 4);
    float* eL  = (float*)alloc(4096 * 4);
    float* eR  = (float*)alloc(4096 * 4);
    float* P   = (float*)alloc((size_t)8 * 8192 * 272 * 4);   // 71.3 MB partials

    k_cvt_x<<<4096, 256, 0, stream>>>(x, xb);
    k_cvt_w<<<512, 256, 0, stream>>>(W, Wbt);
    k_gemm_h<<<dim3(64, 4), 256, 0, stream>>>(xb, Wbt, h, B1t);
    k_st<<<2048, 256, 0, stream>>>(h, a, s, t);
    k_weights<<<32, 256, 0, stream>>>(s, t, wb, eL, eR, B1t);
    k_b2<<<dim3(32, 272), 256, 0, stream>>>(B1t, wb, B2t);
    k_mgemm<<<512, 256, 0, stream>>>(sup, B1t, B2t, P);
    k_out<<<8192, 256, 0, stream>>>(P, eL, eR, outp);
}